// Round 13
// baseline (120.737 us; speedup 1.0000x reference)
//
#include <hip/hip_runtime.h>

// ---------------------------------------------------------------------------
// CausalSelfAttention: x@Wqkv -> split heads -> causal flash attn -> @Wproj
// B=2 T=2048 C=1024 H=16 D=64. All matmuls bf16 MFMA (16x16x32), f32 accum.
// Round 13: (a) revert r12's XCD swizzle (it made every XCD re-fetch all of
// A: 29->63MB, +2us); (b) attn single-buffered K/V -> 35KB LDS -> 4 blocks/
// CU (16 waves/CU): trade the (ineffective, MfmaUtil 15%) intra-block
// prefetch for inter-block TLP to cover the staging drain.
// ---------------------------------------------------------------------------

typedef __attribute__((ext_vector_type(8))) __bf16 bf16x8;
typedef __attribute__((ext_vector_type(4))) __bf16 bf16x4;
typedef __attribute__((ext_vector_type(4))) float f32x4;
typedef __attribute__((ext_vector_type(8))) unsigned short u16x8;
typedef __attribute__((ext_vector_type(4))) unsigned short u16x4;

#define GAS __attribute__((address_space(1)))
#define LAS __attribute__((address_space(3)))

__device__ __forceinline__ unsigned short f2b(float f) {
  unsigned int u = __float_as_uint(f);
  unsigned int r = 0x7FFFu + ((u >> 16) & 1u);
  return (unsigned short)((u + r) >> 16);
}
__device__ __forceinline__ float b2f(unsigned short u) {
  return __uint_as_float((unsigned int)u << 16);
}

// ---------------- prep kernels ----------------

__global__ void cvt_f32_to_bf16(const float* __restrict__ src,
                                unsigned short* __restrict__ dst, int n4) {
  int i = blockIdx.x * blockDim.x + threadIdx.x;
  if (i < n4) {
    float4 v = ((const float4*)src)[i];
    u16x4 o = { f2b(v.x), f2b(v.y), f2b(v.z), f2b(v.w) };
    *(u16x4*)(dst + (size_t)i * 4) = o;
  }
}

// src [K][N] f32  ->  dst [N][K] bf16
__global__ void transpose_f32_to_bf16(const float* __restrict__ src,
                                      unsigned short* __restrict__ dst,
                                      int K, int N) {
  __shared__ float tile[32][33];
  int n0 = blockIdx.x * 32, k0 = blockIdx.y * 32;
  int tx = threadIdx.x, ty = threadIdx.y;  // 32 x 8
#pragma unroll
  for (int i = 0; i < 32; i += 8)
    tile[ty + i][tx] = src[(size_t)(k0 + ty + i) * N + n0 + tx];
  __syncthreads();
#pragma unroll
  for (int i = 0; i < 32; i += 8)
    dst[(size_t)(n0 + ty + i) * K + k0 + tx] = f2b(tile[tx][ty + i]);
}

// ---------------- GEMM: C = A[M,K] * B^T[N,K]^T + bias ----------------
// 128x128 tile, BK=32, 4 waves. Triple-buffered LDS (48KB), prefetch
// distance 2, counted vmcnt(8), chunk^((row>>1)&3) swizzle (linear LDS
// dest, pre-swizzled source; read-side same XOR -> 2-way max = free).
// MODE 0: QKV epilogue -> Q (pre-scaled by 1/sqrt(D)*log2e), K as [B,H,T,D];
//         V as [B,H,D,T] (transposed). Writes re-staged through LDS, 16B
//         coalesced stores. MODE 1: proj epilogue -> f32 natural [M,N].

template <int MODE>
__global__ void __launch_bounds__(256, 3) gemm_bt(
    const unsigned short* __restrict__ A, const unsigned short* __restrict__ Bt,
    const float* __restrict__ bias,
    unsigned short* __restrict__ Oq, unsigned short* __restrict__ Ok,
    unsigned short* __restrict__ Ov, float* __restrict__ Of,
    int M, int N, int K) {
  __shared__ unsigned short smem[3 * 128 * 64];  // 48KB staging / 34.8KB epi
  unsigned short* As = smem;                     // [3][128][32]
  unsigned short* Bs = smem + 3 * 128 * 32;      // [3][128][32]

  const int tid = threadIdx.x;
  const int lane = tid & 63;
  const int wid = tid >> 6;
  const int wr = wid >> 1, wc = wid & 1;
  const int lr = lane & 15, lg = lane >> 4;
  const int m0 = blockIdx.x * 128;
  const int n0 = blockIdx.y * 128;

  f32x4 acc[4][4];
#pragma unroll
  for (int mi = 0; mi < 4; mi++)
#pragma unroll
    for (int ni = 0; ni < 4; ni++) acc[mi][ni] = (f32x4){0.f, 0.f, 0.f, 0.f};

  // stage K-tile t (128x32 each of A,B): 4 global_load_lds per thread.
  // Source chunk-col pre-swizzled by ((row>>1)&3); LDS dest linear.
  auto stage = [&](int t, int buf) {
    const int k0 = t * 32;
    unsigned short* Ad = As + buf * (128 * 32);
    unsigned short* Bd = Bs + buf * (128 * 32);
#pragma unroll
    for (int it = 0; it < 2; ++it) {
      const int chunk_u = it * 256 + (tid & ~63);  // wave-uniform 16B-chunk base
      const int chunk = chunk_u + lane;
      const int row = chunk >> 2;                  // 4 chunks per 32-col row
      const int col = ((chunk & 3) ^ ((row >> 1) & 3)) * 8;  // pre-swizzled
      __builtin_amdgcn_global_load_lds(
          (GAS unsigned int*)(A + (size_t)(m0 + row) * K + k0 + col),
          (LAS unsigned int*)(Ad + chunk_u * 8), 16, 0, 0);
      __builtin_amdgcn_global_load_lds(
          (GAS unsigned int*)(Bt + (size_t)(n0 + row) * K + k0 + col),
          (LAS unsigned int*)(Bd + chunk_u * 8), 16, 0, 0);
    }
  };

  const int kt = K >> 5;
  const int rsw = (lg ^ ((lr >> 1) & 3)) * 8;  // read-side swizzled col

  stage(0, 0);
  stage(1, 1);

  int cur = 0;
  for (int t = 0; t < kt; ++t) {
    __builtin_amdgcn_s_barrier();        // A: step t-1 readers done with buf
    if (t + 2 < kt) {
      int pb = cur + 2; if (pb >= 3) pb -= 3;
      stage(t + 2, pb);                  // prefetch depth 2 stays in flight
      asm volatile("s_waitcnt vmcnt(8)" ::: "memory");  // tile-t loads done
    } else if (t + 1 < kt) {
      asm volatile("s_waitcnt vmcnt(4)" ::: "memory");
    } else {
      asm volatile("s_waitcnt vmcnt(0)" ::: "memory");
    }
    __builtin_amdgcn_s_barrier();        // B: tile t visible to all waves

    const unsigned short* Ab = As + cur * (128 * 32);
    const unsigned short* Bb = Bs + cur * (128 * 32);

    bf16x8 af[4], bfr[4];
#pragma unroll
    for (int mi = 0; mi < 4; mi++)
      af[mi] = *(const bf16x8*)(Ab + (wr * 64 + mi * 16 + lr) * 32 + rsw);
#pragma unroll
    for (int ni = 0; ni < 4; ni++)
      bfr[ni] = *(const bf16x8*)(Bb + (wc * 64 + ni * 16 + lr) * 32 + rsw);
    __builtin_amdgcn_s_setprio(1);
#pragma unroll
    for (int mi = 0; mi < 4; mi++)
#pragma unroll
      for (int ni = 0; ni < 4; ni++)
        acc[mi][ni] = __builtin_amdgcn_mfma_f32_16x16x32_bf16(
            af[mi], bfr[ni], acc[mi][ni], 0, 0, 0);
    __builtin_amdgcn_s_setprio(0);

    cur += 1; if (cur >= 3) cur -= 3;
  }

  const float SCLQ = 0.125f * 1.44269504088896340736f;  // 1/sqrt(64)*log2(e)

  if constexpr (MODE == 1) {
#pragma unroll
    for (int mi = 0; mi < 4; mi++) {
#pragma unroll
      for (int ni = 0; ni < 4; ni++) {
        const int nn = n0 + wc * 64 + ni * 16 + lr;
        const float bv = bias[nn];
#pragma unroll
        for (int r = 0; r < 4; r++) {
          const int mm = m0 + wr * 64 + mi * 16 + lg * 4 + r;
          Of[(size_t)mm * N + nn] = acc[mi][ni][r] + bv;
        }
      }
    }
  } else {
    // QKV epilogue: re-stage through LDS (reuse smem), write coalesced.
    unsigned short* L = smem;            // [128][136] bf16 (pad breaks banks)
    const int which = n0 >> 10;          // block-uniform third (0=Q,1=K,2=V)
    const float sc = (which == 0) ? SCLQ : 1.0f;
    __syncthreads();                     // all waves done reading As/Bs
#pragma unroll
    for (int mi = 0; mi < 4; mi++) {
#pragma unroll
      for (int ni = 0; ni < 4; ni++) {
        const int nn_l = wc * 64 + ni * 16 + lr;
        const float bv = bias[n0 + nn_l];
#pragma unroll
        for (int r = 0; r < 4; r++) {
          const int mm_l = wr * 64 + mi * 16 + lg * 4 + r;
          const unsigned short v = f2b((acc[mi][ni][r] + bv) * sc);
          if (which == 2) L[nn_l * 136 + mm_l] = v;   // V: store transposed
          else            L[mm_l * 136 + nn_l] = v;   // Q,K: natural
        }
      }
    }
    __syncthreads();
    const int b = m0 >> 11;
    const int t0 = m0 & 2047;
    const int h0 = (n0 & 1023) >> 6;
    if (which == 2) {
      const int row = tid >> 1;          // (hsub,d): 2 heads x 64 d
      const int hsub = row >> 6, d = row & 63;
      const int tt0 = (tid & 1) * 64;
      const unsigned short* src = L + row * 136 + tt0;
      unsigned short* dst = Ov +
          ((size_t)((b * 16 + h0 + hsub) * 64 + d)) * 2048 + t0 + tt0;
#pragma unroll
      for (int j = 0; j < 8; j++)
        *(u16x8*)(dst + j * 8) = *(const u16x8*)(src + j * 8);
    } else {
      const int mm_l = tid & 127;
      const int hsub = tid >> 7;
      const unsigned short* src = L + mm_l * 136 + hsub * 64;
      unsigned short* base = (which == 0) ? Oq : Ok;
      unsigned short* dst = base +
          ((size_t)(b * 16 + h0 + hsub) * 2048 + t0 + mm_l) * 64;
#pragma unroll
      for (int j = 0; j < 8; j++)
        *(u16x8*)(dst + j * 8) = *(const u16x8*)(src + j * 8);
    }
  }
}

// ---------------- flash attention (causal, KV-split) ----------------
// 896 blocks = 28 classes x 32 (b,h); 256 threads = 4 waves x 32 q-rows.
// SINGLE-buffered K [64t][64d] and V^T [64d][64t] (35KB LDS -> 4 blocks/CU,
// 16 waves/CU: staging drain covered by inter-block TLP). Swapped QK^T:
// s = mfma(K, Q) puts qrow on lane (col=lr), keys on regs -> scalar m/l per
// lane, P packed as b64 writes (k^((lr&3)<<4) swizzle, same mask on reads),
// l-reduce deferred to epilogue. Classes/split/merge identical to round 7.

__global__ void __launch_bounds__(256, 4) attn_kernel(
    const unsigned short* __restrict__ Qh, const unsigned short* __restrict__ Kh,
    const unsigned short* __restrict__ Vh, unsigned short* __restrict__ yatt,
    unsigned short* __restrict__ Opart, float* __restrict__ Mp,
    float* __restrict__ Lp) {
  __shared__ unsigned short KsL[64 * 64];
  __shared__ unsigned short VsL[64 * 64];
  __shared__ unsigned short Pl[4 * 32 * 72];

  const int tid = threadIdx.x;
  const int lane = tid & 63;
  const int w = tid >> 6;                 // 0..3
  const int lr = lane & 15, lg = lane >> 4;

  const int cls = blockIdx.x >> 5;        // 0..27, sorted desc by work
  const int bh = blockIdx.x & 31;
  const int hh = bh & 15;
  const int bb = bh >> 4;

  // class tables packed as nibbles / 2-bit fields (no runtime-indexed array)
  const unsigned long long QA = 0x8899AABBCCDDEEFFull;   // qt for cls 0..15
  const unsigned long long QB = 0x0000014425566377ull;   // qt for cls 16..27
  const unsigned long long KK = 0x00A4912444444444ull;   // kind 2b: 0=L,1=R,2=U
  const int qt = (cls < 16) ? (int)((QA >> (4 * cls)) & 15)
                            : (int)((QB >> (4 * (cls - 16))) & 15);
  const int kind = (int)((KK >> (2 * cls)) & 3);
  const int t0 = (kind == 1) ? (qt + 1) : 0;
  const int t1 = (kind == 0) ? (qt + 1) : (2 * qt + 2);

  const size_t head_base = ((size_t)(bb * 16 + hh)) * 2048 * 64;
  const unsigned short* Qg = Qh + head_base;
  const unsigned short* Kg = Kh + head_base;
  const unsigned short* Vg = Vh + head_base;  // [D=64][T=2048] within head

  const int q0 = qt * 128 + w * 32;           // wave's first q-row (32 rows)
  const int diagw = 2 * qt + (w >> 1);        // wave's diagonal KV-tile index

  // Q fragments: half A rows q0+lr, half B rows q0+16+lr (B-operand layout)
  bf16x8 aqA0 = *(const bf16x8*)(Qg + (size_t)(q0 + lr) * 64 + lg * 8);
  bf16x8 aqA1 = *(const bf16x8*)(Qg + (size_t)(q0 + lr) * 64 + 32 + lg * 8);
  bf16x8 aqB0 = *(const bf16x8*)(Qg + (size_t)(q0 + 16 + lr) * 64 + lg * 8);
  bf16x8 aqB1 = *(const bf16x8*)(Qg + (size_t)(q0 + 16 + lr) * 64 + 32 + lg * 8);

  float mA = -__builtin_inff(), mB = -__builtin_inff();
  float lA = 0.f, lB = 0.f;                   // lane-local partial row sums
  f32x4 oA[4], oB[4];
#pragma unroll
  for (int dj = 0; dj < 4; dj++) {
    oA[dj] = (f32x4){0.f, 0.f, 0.f, 0.f};
    oB[dj] = (f32x4){0.f, 0.f, 0.f, 0.f};
  }

  // staging: 256 threads x 2 chunks each per array
  auto stage = [&](int kv0) {
#pragma unroll
    for (int it = 0; it < 2; ++it) {
      const int chunk_u = it * 256 + (tid & ~63);  // wave-uniform base
      const int chunk = chunk_u + lane;
      const int row = chunk >> 3;
      const int col = ((chunk & 7) ^ (row & 7)) << 3;  // pre-swizzled src col
      __builtin_amdgcn_global_load_lds(
          (GAS unsigned int*)(Kg + (size_t)(kv0 + row) * 64 + col),
          (LAS unsigned int*)(KsL + chunk_u * 8), 16, 0, 0);
      __builtin_amdgcn_global_load_lds(
          (GAS unsigned int*)(Vg + (size_t)row * 2048 + kv0 + col),
          (LAS unsigned int*)(VsL + chunk_u * 8), 16, 0, 0);
    }
  };

  __bf16* Pw = (__bf16*)(Pl + w * 32 * 72);
  const int swr = (lr & 7) << 3;   // read-side XOR for K/V row (nj*16+lr)
  const int pswz = (lr & 3) << 4;  // P-path XOR (write & read, rule #21)

  for (int i = t0; i < t1; ++i) {
    __builtin_amdgcn_s_barrier();        // A: all waves done reading prev tile
    stage(i * 64);
    asm volatile("s_waitcnt vmcnt(0)" ::: "memory");  // own loads landed
    __builtin_amdgcn_s_barrier();        // B: tile i visible to all waves

    if (i <= diagw) {                    // wave-uniform: skip masked tiles
      const int kv0 = i * 64;
      const unsigned short* Kb = KsL;
      const unsigned short* Vb = VsL;

      // swapped QK^T: s = mfma(K, Q) -> col=lr=qrow, row=lg*4+r=key offset
      f32x4 sA[4], sB[4];
      __builtin_amdgcn_s_setprio(1);
#pragma unroll
      for (int nj = 0; nj < 4; nj++) {
        const unsigned short* krow = Kb + (nj * 16 + lr) * 64;
        bf16x8 kb0 = *(const bf16x8*)(krow + ((lg * 8) ^ swr));
        bf16x8 kb1 = *(const bf16x8*)(krow + ((32 + lg * 8) ^ swr));
        f32x4 zA = (f32x4){0.f, 0.f, 0.f, 0.f};
        f32x4 zB = (f32x4){0.f, 0.f, 0.f, 0.f};
        zA = __builtin_amdgcn_mfma_f32_16x16x32_bf16(kb0, aqA0, zA, 0, 0, 0);
        zA = __builtin_amdgcn_mfma_f32_16x16x32_bf16(kb1, aqA1, zA, 0, 0, 0);
        zB = __builtin_amdgcn_mfma_f32_16x16x32_bf16(kb0, aqB0, zB, 0, 0, 0);
        zB = __builtin_amdgcn_mfma_f32_16x16x32_bf16(kb1, aqB1, zB, 0, 0, 0);
        sA[nj] = zA;
        sB[nj] = zB;
      }
      __builtin_amdgcn_s_setprio(0);

      // causal mask only on the wave's diagonal tile
      if (i == diagw) {
        const int qrA = q0 + lr, qrB = q0 + 16 + lr;
#pragma unroll
        for (int nj = 0; nj < 4; nj++) {
#pragma unroll
          for (int r = 0; r < 4; r++) {
            const int key = kv0 + nj * 16 + lg * 4 + r;
            if (key > qrA) sA[nj][r] = -__builtin_inff();
            if (key > qrB) sB[nj][r] = -__builtin_inff();
          }
        }
      }

      // lane-local per-row max (lane owns 16 of row's 64 keys)
      float pmA = sA[0][0], pmB = sB[0][0];
#pragma unroll
      for (int nj = 0; nj < 4; nj++)
#pragma unroll
        for (int r = 0; r < 4; r++) {
          pmA = fmaxf(pmA, sA[nj][r]);
          pmB = fmaxf(pmB, sB[nj][r]);
        }

      // defer-max (T13, THR=8): row max <= m+8 iff all 4 owner lanes agree
      const bool okl = (pmA <= mA + 8.f) & (pmB <= mB + 8.f);
      if (!__all(okl)) {                 // rare: first tile + rare growth
        // full row max across the 4 owner lanes (xor 16, 32)
        pmA = fmaxf(pmA, __shfl_xor(pmA, 16));
        pmA = fmaxf(pmA, __shfl_xor(pmA, 32));
        pmB = fmaxf(pmB, __shfl_xor(pmB, 16));
        pmB = fmaxf(pmB, __shfl_xor(pmB, 32));
        const float mnA = fmaxf(mA, pmA), mnB = fmaxf(mB, pmB);
        const float scA = exp2f(mA - mnA), scB = exp2f(mB - mnB);
        mA = mnA; mB = mnB;
        lA *= scA; lB *= scB;
#pragma unroll
        for (int r = 0; r < 4; r++) {
          const float cA = __shfl(scA, lg * 4 + r);  // sc of row lg*4+r
          const float cB = __shfl(scB, lg * 4 + r);
#pragma unroll
          for (int dj = 0; dj < 4; dj++) {
            oA[dj][r] *= cA;
            oB[dj][r] *= cB;
          }
        }
      }

      // P = exp2(s - m) -> bf16x4 packed swizzled writes
#pragma unroll
      for (int nj = 0; nj < 4; nj++) {
        const float a0 = exp2f(sA[nj][0] - mA), a1 = exp2f(sA[nj][1] - mA);
        const float a2 = exp2f(sA[nj][2] - mA), a3 = exp2f(sA[nj][3] - mA);
        lA += (a0 + a1) + (a2 + a3);
        bf16x4 pkA = {(__bf16)a0, (__bf16)a1, (__bf16)a2, (__bf16)a3};
        *(bf16x4*)(Pw + lr * 72 + ((nj * 16 + lg * 4) ^ pswz)) = pkA;
        const float b0 = exp2f(sB[nj][0] - mB), b1 = exp2f(sB[nj][1] - mB);
        const float b2 = exp2f(sB[nj][2] - mB), b3 = exp2f(sB[nj][3] - mB);
        lB += (b0 + b1) + (b2 + b3);
        bf16x4 pkB = {(__bf16)b0, (__bf16)b1, (__bf16)b2, (__bf16)b3};
        *(bf16x4*)(Pw + (16 + lr) * 72 + ((nj * 16 + lg * 4) ^ pswz)) = pkB;
      }

      // PV A-fragments (same swizzle mask on reads; in-wave DS ordering)
      bf16x8 paA0 = *(const bf16x8*)(Pw + lr * 72 + ((lg * 8) ^ pswz));
      bf16x8 paA1 = *(const bf16x8*)(Pw + lr * 72 + ((32 + lg * 8) ^ pswz));
      bf16x8 paB0 = *(const bf16x8*)(Pw + (16 + lr) * 72 + ((lg * 8) ^ pswz));
      bf16x8 paB1 = *(const bf16x8*)(Pw + (16 + lr) * 72 + ((32 + lg * 8) ^ pswz));

      // PV: O += P[32,64] * V^T (vb shared across halves)
      __builtin_amdgcn_s_setprio(1);
#pragma unroll
      for (int dj = 0; dj < 4; dj++) {
        const unsigned short* vrow = Vb + (dj * 16 + lr) * 64;
        bf16x8 vb0 = *(const bf16x8*)(vrow + ((lg * 8) ^ swr));
        bf16x8 vb1 = *(const bf16x8*)(vrow + ((32 + lg * 8) ^ swr));
        oA[dj] = __builtin_amdgcn_mfma_f32_16x16x32_bf16(paA0, vb0, oA[dj], 0, 0, 0);
        oA[dj] = __builtin_amdgcn_mfma_f32_16x16x32_bf16(paA1, vb1, oA[dj], 0, 0, 0);
        oB[dj] = __builtin_amdgcn_mfma_f32_16x16x32_bf16(paB0, vb0, oB[dj], 0, 0, 0);
        oB[dj] = __builtin_amdgcn_mfma_f32_16x16x32_bf16(paB1, vb1, oB[dj], 0, 0, 0);
      }
      __builtin_amdgcn_s_setprio(0);
    }
  }

  // finalize l: full row sums (partials live on the 4 owner lanes)
  lA += __shfl_xor(lA, 16); lA += __shfl_xor(lA, 32);
  lB += __shfl_xor(lB, 16); lB += __shfl_xor(lB, 32);

  if (kind == 2) {
    // unsplit: normalize, write bf16 [B,T,C] (heads re-merged)
    __bf16* yb = (__bf16*)yatt;
#pragma unroll
    for (int r = 0; r < 4; r++) {
      const float invA = 1.0f / __shfl(lA, lg * 4 + r);
      const float invB = 1.0f / __shfl(lB, lg * 4 + r);
      const int tA = q0 + lg * 4 + r;
      const int tB = tA + 16;
      const size_t baseA = ((size_t)(bb * 2048 + tA)) * 1024 + hh * 64;
      const size_t baseB = ((size_t)(bb * 2048 + tB)) * 1024 + hh * 64;
#pragma unroll
      for (int dj = 0; dj < 4; dj++) {
        yb[baseA + dj * 16 + lr] = (__bf16)(oA[dj][r] * invA);
        yb[baseB + dj * 16 + lr] = (__bf16)(oB[dj][r] * invB);
      }
    }
  } else {
    // split half: write unnormalized partial O (bf16) + m,l (f32)
    __bf16* Ob = (__bf16*)Opart;
#pragma unroll
    for (int r = 0; r < 4; r++) {
      const int slotA = bh * 1536 + (q0 + lg * 4 + r) - 512;
      const int slotB = slotA + 16;
      const size_t baseA = ((size_t)(kind * 49152 + slotA)) * 64;
      const size_t baseB = ((size_t)(kind * 49152 + slotB)) * 64;
#pragma unroll
      for (int dj = 0; dj < 4; dj++) {
        Ob[baseA + dj * 16 + lr] = (__bf16)oA[dj][r];
        Ob[baseB + dj * 16 + lr] = (__bf16)oB[dj][r];
      }
    }
    if (lg == 0) {                       // one writer per row
      const int slA = bh * 1536 + (q0 + lr) - 512;
      Mp[kind * 49152 + slA] = mA;
      Lp[kind * 49152 + slA] = lA;
      Mp[kind * 49152 + slA + 16] = mB;
      Lp[kind * 49152 + slA + 16] = lB;
    }
  }
}

// combine L/R partials: y = (O1*2^(m1-m) + O2*2^(m2-m)) / (l1*2^(m1-m)+l2*2^(m2-m))
__global__ void __launch_bounds__(256) attn_merge(
    const unsigned short* __restrict__ Op, const float* __restrict__ Mp,
    const float* __restrict__ Lp, unsigned short* __restrict__ yatt) {
  const int gid = blockIdx.x * 256 + threadIdx.x;  // 48*256 = 12288 per bh
  const int sl = gid >> 3;                         // 0..1535
  const int d0 = (gid & 7) * 8;
  const int bh = blockIdx.y;
  const int slot = bh * 1536 + sl;
  const float m1 = Mp[slot], m2 = Mp[49152 + slot];
  const float l1 = Lp[slot], l2 = Lp[49152 + slot];
  const float mx = fmaxf(m1, m2);
  const float w1 = exp2f(m1 - mx), w2 = exp2f(m2 - mx);
  const float inv = 1.0f / (l1 * w1 + l2 * w2);
  u16x8 a = *(const u16x8*)(Op + (size_t)slot * 64 + d0);
  u16x8 b = *(const u16x8*)(Op + (size_t)(49152 + slot) * 64 + d0);
  const int qr = 512 + sl;
  unsigned short* dst = yatt +
      ((size_t)((bh >> 4) * 2048 + qr)) * 1024 + (bh & 15) * 64 + d0;
  u16x8 o;
#pragma unroll
  for (int j = 0; j < 8; j++)
    o[j] = f2b((b2f(a[j]) * w1 + b2f(b[j]) * w2) * inv);
  *(u16x8*)dst = o;
}

// ---------------- launcher ----------------

extern "C" void kernel_launch(void* const* d_in, const int* in_sizes, int n_in,
                              void* d_out, int out_size, void* d_ws,
                              size_t ws_size, hipStream_t stream) {
  (void)in_sizes; (void)n_in; (void)out_size; (void)ws_size;
  const float* x      = (const float*)d_in[0];  // [2,2048,1024]
  const float* w_qkv  = (const float*)d_in[1];  // [1024,3072]
  const float* b_qkv  = (const float*)d_in[2];  // [3072]
  const float* w_proj = (const float*)d_in[3];  // [1024,1024]
  const float* b_proj = (const float*)d_in[4];  // [1024]
  float* out = (float*)d_out;                   // [2,2048,1024] f32

  unsigned short* ws     = (unsigned short*)d_ws;
  unsigned short* xb     = ws;                                  // 4096*1024
  unsigned short* wqkvT  = xb     + (size_t)4096 * 1024;        // 3072*1024
  unsigned short* wprojT = wqkvT  + (size_t)3072 * 1024;        // 1024*1024
  unsigned short* Qh     = wprojT + (size_t)1024 * 1024;        // 2*16*2048*64
  unsigned short* Kh     = Qh     + (size_t)2 * 16 * 2048 * 64;
  unsigned short* Vh     = Kh     + (size_t)2 * 16 * 2048 * 64; // [B,H,D,T]
  unsigned short* yatt   = Vh     + (size_t)2 * 16 * 2048 * 64; // 4096*1024

  // attn partials alias xb/wqkvT (dead after QKV GEMM); wprojT untouched.
  unsigned short* Opart = ws;                      // [2][49152][64] bf16
  float* Mp = (float*)(ws + (size_t)6291456);      // [2][49152] f32
  float* Lp = Mp + 2 * 49152;                      // [2][49152] f32

  cvt_f32_to_bf16<<<4096, 256, 0, stream>>>(x, xb, 1048576);
  transpose_f32_to_bf16<<<dim3(96, 32), dim3(32, 8), 0, stream>>>(w_qkv, wqkvT, 1024, 3072);
  transpose_f32_to_bf16<<<dim3(32, 32), dim3(32, 8), 0, stream>>>(w_proj, wprojT, 1024, 1024);

  gemm_bt<0><<<dim3(32, 24), 256, 0, stream>>>(xb, wqkvT, b_qkv, Qh, Kh, Vh,
                                               nullptr, 4096, 3072, 1024);
  attn_kernel<<<896, 256, 0, stream>>>(Qh, Kh, Vh, yatt, Opart, Mp, Lp);
  attn_merge<<<dim3(48, 32), 256, 0, stream>>>(Opart, Mp, Lp, yatt);
  gemm_bt<1><<<dim3(32, 8), 256, 0, stream>>>(yatt, wprojT, b_proj, nullptr,
                                              nullptr, nullptr, out, 4096, 1024, 1024);
}

// Round 14
// 114.629 us; speedup vs baseline: 1.0533x; 1.0533x over previous
//
#include <hip/hip_runtime.h>

// ---------------------------------------------------------------------------
// CausalSelfAttention: x@Wqkv -> split heads -> causal flash attn -> @Wproj
// B=2 T=2048 C=1024 H=16 D=64. All matmuls bf16 MFMA (16x16x32), f32 accum.
// Round 14: consolidate at the round-10 best (116.0us): r10 GEMM (BK=32,
// 3-buf, prefetch-2, correct swizzle, no XCD remap) + r10 attn (dbuf KV,
// counted vmcnt(4)). One experiment: drop s_setprio from the lockstep GEMMs
// (m190: null-to-negative without phase-split). Attn keeps setprio (m191).
// ---------------------------------------------------------------------------

typedef __attribute__((ext_vector_type(8))) __bf16 bf16x8;
typedef __attribute__((ext_vector_type(4))) __bf16 bf16x4;
typedef __attribute__((ext_vector_type(4))) float f32x4;
typedef __attribute__((ext_vector_type(8))) unsigned short u16x8;
typedef __attribute__((ext_vector_type(4))) unsigned short u16x4;

#define GAS __attribute__((address_space(1)))
#define LAS __attribute__((address_space(3)))

__device__ __forceinline__ unsigned short f2b(float f) {
  unsigned int u = __float_as_uint(f);
  unsigned int r = 0x7FFFu + ((u >> 16) & 1u);
  return (unsigned short)((u + r) >> 16);
}
__device__ __forceinline__ float b2f(unsigned short u) {
  return __uint_as_float((unsigned int)u << 16);
}

// ---------------- prep kernels ----------------

__global__ void cvt_f32_to_bf16(const float* __restrict__ src,
                                unsigned short* __restrict__ dst, int n4) {
  int i = blockIdx.x * blockDim.x + threadIdx.x;
  if (i < n4) {
    float4 v = ((const float4*)src)[i];
    u16x4 o = { f2b(v.x), f2b(v.y), f2b(v.z), f2b(v.w) };
    *(u16x4*)(dst + (size_t)i * 4) = o;
  }
}

// src [K][N] f32  ->  dst [N][K] bf16
__global__ void transpose_f32_to_bf16(const float* __restrict__ src,
                                      unsigned short* __restrict__ dst,
                                      int K, int N) {
  __shared__ float tile[32][33];
  int n0 = blockIdx.x * 32, k0 = blockIdx.y * 32;
  int tx = threadIdx.x, ty = threadIdx.y;  // 32 x 8
#pragma unroll
  for (int i = 0; i < 32; i += 8)
    tile[ty + i][tx] = src[(size_t)(k0 + ty + i) * N + n0 + tx];
  __syncthreads();
#pragma unroll
  for (int i = 0; i < 32; i += 8)
    dst[(size_t)(n0 + ty + i) * K + k0 + tx] = f2b(tile[tx][ty + i]);
}

// ---------------- GEMM: C = A[M,K] * B^T[N,K]^T + bias ----------------
// 128x128 tile, BK=32, 4 waves. Triple-buffered LDS (48KB), prefetch
// distance 2, counted vmcnt(8), chunk^((row>>1)&3) swizzle (linear LDS
// dest, pre-swizzled source; read-side same XOR -> 2-way max = free).
// MODE 0: QKV epilogue -> Q (pre-scaled by 1/sqrt(D)*log2e), K as [B,H,T,D];
//         V as [B,H,D,T] (transposed). Writes re-staged through LDS, 16B
//         coalesced stores. MODE 1: proj epilogue -> f32 natural [M,N].

template <int MODE>
__global__ void __launch_bounds__(256, 3) gemm_bt(
    const unsigned short* __restrict__ A, const unsigned short* __restrict__ Bt,
    const float* __restrict__ bias,
    unsigned short* __restrict__ Oq, unsigned short* __restrict__ Ok,
    unsigned short* __restrict__ Ov, float* __restrict__ Of,
    int M, int N, int K) {
  __shared__ unsigned short smem[3 * 128 * 64];  // 48KB staging / 34.8KB epi
  unsigned short* As = smem;                     // [3][128][32]
  unsigned short* Bs = smem + 3 * 128 * 32;      // [3][128][32]

  const int tid = threadIdx.x;
  const int lane = tid & 63;
  const int wid = tid >> 6;
  const int wr = wid >> 1, wc = wid & 1;
  const int lr = lane & 15, lg = lane >> 4;
  const int m0 = blockIdx.x * 128;
  const int n0 = blockIdx.y * 128;

  f32x4 acc[4][4];
#pragma unroll
  for (int mi = 0; mi < 4; mi++)
#pragma unroll
    for (int ni = 0; ni < 4; ni++) acc[mi][ni] = (f32x4){0.f, 0.f, 0.f, 0.f};

  // stage K-tile t (128x32 each of A,B): 4 global_load_lds per thread.
  // Source chunk-col pre-swizzled by ((row>>1)&3); LDS dest linear.
  auto stage = [&](int t, int buf) {
    const int k0 = t * 32;
    unsigned short* Ad = As + buf * (128 * 32);
    unsigned short* Bd = Bs + buf * (128 * 32);
#pragma unroll
    for (int it = 0; it < 2; ++it) {
      const int chunk_u = it * 256 + (tid & ~63);  // wave-uniform 16B-chunk base
      const int chunk = chunk_u + lane;
      const int row = chunk >> 2;                  // 4 chunks per 32-col row
      const int col = ((chunk & 3) ^ ((row >> 1) & 3)) * 8;  // pre-swizzled
      __builtin_amdgcn_global_load_lds(
          (GAS unsigned int*)(A + (size_t)(m0 + row) * K + k0 + col),
          (LAS unsigned int*)(Ad + chunk_u * 8), 16, 0, 0);
      __builtin_amdgcn_global_load_lds(
          (GAS unsigned int*)(Bt + (size_t)(n0 + row) * K + k0 + col),
          (LAS unsigned int*)(Bd + chunk_u * 8), 16, 0, 0);
    }
  };

  const int kt = K >> 5;
  const int rsw = (lg ^ ((lr >> 1) & 3)) * 8;  // read-side swizzled col

  stage(0, 0);
  stage(1, 1);

  int cur = 0;
  for (int t = 0; t < kt; ++t) {
    __builtin_amdgcn_s_barrier();        // A: step t-1 readers done with buf
    if (t + 2 < kt) {
      int pb = cur + 2; if (pb >= 3) pb -= 3;
      stage(t + 2, pb);                  // prefetch depth 2 stays in flight
      asm volatile("s_waitcnt vmcnt(8)" ::: "memory");  // tile-t loads done
    } else if (t + 1 < kt) {
      asm volatile("s_waitcnt vmcnt(4)" ::: "memory");
    } else {
      asm volatile("s_waitcnt vmcnt(0)" ::: "memory");
    }
    __builtin_amdgcn_s_barrier();        // B: tile t visible to all waves

    const unsigned short* Ab = As + cur * (128 * 32);
    const unsigned short* Bb = Bs + cur * (128 * 32);

    bf16x8 af[4], bfr[4];
#pragma unroll
    for (int mi = 0; mi < 4; mi++)
      af[mi] = *(const bf16x8*)(Ab + (wr * 64 + mi * 16 + lr) * 32 + rsw);
#pragma unroll
    for (int ni = 0; ni < 4; ni++)
      bfr[ni] = *(const bf16x8*)(Bb + (wc * 64 + ni * 16 + lr) * 32 + rsw);
#pragma unroll
    for (int mi = 0; mi < 4; mi++)
#pragma unroll
      for (int ni = 0; ni < 4; ni++)
        acc[mi][ni] = __builtin_amdgcn_mfma_f32_16x16x32_bf16(
            af[mi], bfr[ni], acc[mi][ni], 0, 0, 0);

    cur += 1; if (cur >= 3) cur -= 3;
  }

  const float SCLQ = 0.125f * 1.44269504088896340736f;  // 1/sqrt(64)*log2(e)

  if constexpr (MODE == 1) {
#pragma unroll
    for (int mi = 0; mi < 4; mi++) {
#pragma unroll
      for (int ni = 0; ni < 4; ni++) {
        const int nn = n0 + wc * 64 + ni * 16 + lr;
        const float bv = bias[nn];
#pragma unroll
        for (int r = 0; r < 4; r++) {
          const int mm = m0 + wr * 64 + mi * 16 + lg * 4 + r;
          Of[(size_t)mm * N + nn] = acc[mi][ni][r] + bv;
        }
      }
    }
  } else {
    // QKV epilogue: re-stage through LDS (reuse smem), write coalesced.
    unsigned short* L = smem;            // [128][136] bf16 (pad breaks banks)
    const int which = n0 >> 10;          // block-uniform third (0=Q,1=K,2=V)
    const float sc = (which == 0) ? SCLQ : 1.0f;
    __syncthreads();                     // all waves done reading As/Bs
#pragma unroll
    for (int mi = 0; mi < 4; mi++) {
#pragma unroll
      for (int ni = 0; ni < 4; ni++) {
        const int nn_l = wc * 64 + ni * 16 + lr;
        const float bv = bias[n0 + nn_l];
#pragma unroll
        for (int r = 0; r < 4; r++) {
          const int mm_l = wr * 64 + mi * 16 + lg * 4 + r;
          const unsigned short v = f2b((acc[mi][ni][r] + bv) * sc);
          if (which == 2) L[nn_l * 136 + mm_l] = v;   // V: store transposed
          else            L[mm_l * 136 + nn_l] = v;   // Q,K: natural
        }
      }
    }
    __syncthreads();
    const int b = m0 >> 11;
    const int t0 = m0 & 2047;
    const int h0 = (n0 & 1023) >> 6;
    if (which == 2) {
      const int row = tid >> 1;          // (hsub,d): 2 heads x 64 d
      const int hsub = row >> 6, d = row & 63;
      const int tt0 = (tid & 1) * 64;
      const unsigned short* src = L + row * 136 + tt0;
      unsigned short* dst = Ov +
          ((size_t)((b * 16 + h0 + hsub) * 64 + d)) * 2048 + t0 + tt0;
#pragma unroll
      for (int j = 0; j < 8; j++)
        *(u16x8*)(dst + j * 8) = *(const u16x8*)(src + j * 8);
    } else {
      const int mm_l = tid & 127;
      const int hsub = tid >> 7;
      const unsigned short* src = L + mm_l * 136 + hsub * 64;
      unsigned short* base = (which == 0) ? Oq : Ok;
      unsigned short* dst = base +
          ((size_t)(b * 16 + h0 + hsub) * 2048 + t0 + mm_l) * 64;
#pragma unroll
      for (int j = 0; j < 8; j++)
        *(u16x8*)(dst + j * 8) = *(const u16x8*)(src + j * 8);
    }
  }
}

// ---------------- flash attention (causal, KV-split) ----------------
// 896 blocks = 28 classes x 32 (b,h); 256 threads = 4 waves x 32 q-rows.
// Swapped QK^T: s = mfma(K, Q) puts qrow on lane (col=lr), keys on regs ->
// scalar m/l per lane, P packed as b64 writes (k ^ ((lr&3)<<4) swizzle,
// same mask on reads), l-reduce deferred to epilogue. K [64t][64d] and
// V^T [64d][64t] staged via global_load_lds + XOR swizzle, dbuf, counted
// vmcnt(4). Classes/split/merge identical to round 7.

__global__ void __launch_bounds__(256, 3) attn_kernel(
    const unsigned short* __restrict__ Qh, const unsigned short* __restrict__ Kh,
    const unsigned short* __restrict__ Vh, unsigned short* __restrict__ yatt,
    unsigned short* __restrict__ Opart, float* __restrict__ Mp,
    float* __restrict__ Lp) {
  __shared__ unsigned short KsL[2 * 64 * 64];
  __shared__ unsigned short VsL[2 * 64 * 64];
  __shared__ unsigned short Pl[4 * 32 * 72];

  const int tid = threadIdx.x;
  const int lane = tid & 63;
  const int w = tid >> 6;                 // 0..3
  const int lr = lane & 15, lg = lane >> 4;

  const int cls = blockIdx.x >> 5;        // 0..27, sorted desc by work
  const int bh = blockIdx.x & 31;
  const int hh = bh & 15;
  const int bb = bh >> 4;

  // class tables packed as nibbles / 2-bit fields (no runtime-indexed array)
  const unsigned long long QA = 0x8899AABBCCDDEEFFull;   // qt for cls 0..15
  const unsigned long long QB = 0x0000014425566377ull;   // qt for cls 16..27
  const unsigned long long KK = 0x00A4912444444444ull;   // kind 2b: 0=L,1=R,2=U
  const int qt = (cls < 16) ? (int)((QA >> (4 * cls)) & 15)
                            : (int)((QB >> (4 * (cls - 16))) & 15);
  const int kind = (int)((KK >> (2 * cls)) & 3);
  const int t0 = (kind == 1) ? (qt + 1) : 0;
  const int t1 = (kind == 0) ? (qt + 1) : (2 * qt + 2);

  const size_t head_base = ((size_t)(bb * 16 + hh)) * 2048 * 64;
  const unsigned short* Qg = Qh + head_base;
  const unsigned short* Kg = Kh + head_base;
  const unsigned short* Vg = Vh + head_base;  // [D=64][T=2048] within head

  const int q0 = qt * 128 + w * 32;           // wave's first q-row (32 rows)
  const int diagw = 2 * qt + (w >> 1);        // wave's diagonal KV-tile index

  // Q fragments: half A rows q0+lr, half B rows q0+16+lr (B-operand layout)
  bf16x8 aqA0 = *(const bf16x8*)(Qg + (size_t)(q0 + lr) * 64 + lg * 8);
  bf16x8 aqA1 = *(const bf16x8*)(Qg + (size_t)(q0 + lr) * 64 + 32 + lg * 8);
  bf16x8 aqB0 = *(const bf16x8*)(Qg + (size_t)(q0 + 16 + lr) * 64 + lg * 8);
  bf16x8 aqB1 = *(const bf16x8*)(Qg + (size_t)(q0 + 16 + lr) * 64 + 32 + lg * 8);

  float mA = -__builtin_inff(), mB = -__builtin_inff();
  float lA = 0.f, lB = 0.f;                   // lane-local partial row sums
  f32x4 oA[4], oB[4];
#pragma unroll
  for (int dj = 0; dj < 4; dj++) {
    oA[dj] = (f32x4){0.f, 0.f, 0.f, 0.f};
    oB[dj] = (f32x4){0.f, 0.f, 0.f, 0.f};
  }

  // staging: 256 threads x 2 chunks each per array
  auto stage = [&](int kv0, int buf) {
    unsigned short* Kd = KsL + buf * (64 * 64);
    unsigned short* Vd = VsL + buf * (64 * 64);
#pragma unroll
    for (int it = 0; it < 2; ++it) {
      const int chunk_u = it * 256 + (tid & ~63);  // wave-uniform base
      const int chunk = chunk_u + lane;
      const int row = chunk >> 3;
      const int col = ((chunk & 7) ^ (row & 7)) << 3;  // pre-swizzled src col
      __builtin_amdgcn_global_load_lds(
          (GAS unsigned int*)(Kg + (size_t)(kv0 + row) * 64 + col),
          (LAS unsigned int*)(Kd + chunk_u * 8), 16, 0, 0);
      __builtin_amdgcn_global_load_lds(
          (GAS unsigned int*)(Vg + (size_t)row * 2048 + kv0 + col),
          (LAS unsigned int*)(Vd + chunk_u * 8), 16, 0, 0);
    }
  };

  __bf16* Pw = (__bf16*)(Pl + w * 32 * 72);
  const int swr = (lr & 7) << 3;   // read-side XOR for K/V row (nj*16+lr)
  const int pswz = (lr & 3) << 4;  // P-path XOR (write & read, rule #21)

  stage(t0 * 64, t0 & 1);

  for (int i = t0; i < t1; ++i) {
    const int cur = i & 1;
    __builtin_amdgcn_s_barrier();        // A: protect buf cur^1
    if (i + 1 < t1) {
      stage((i + 1) * 64, cur ^ 1);      // prefetch stays in flight (T4)
      asm volatile("s_waitcnt vmcnt(4)" ::: "memory");  // tile-i loads done
    } else {
      asm volatile("s_waitcnt vmcnt(0)" ::: "memory");
    }
    __builtin_amdgcn_s_barrier();        // B: tile i visible

    if (i <= diagw) {                    // wave-uniform: skip masked tiles
      const int kv0 = i * 64;
      const unsigned short* Kb = KsL + cur * (64 * 64);
      const unsigned short* Vb = VsL + cur * (64 * 64);

      // swapped QK^T: s = mfma(K, Q) -> col=lr=qrow, row=lg*4+r=key offset
      f32x4 sA[4], sB[4];
      __builtin_amdgcn_s_setprio(1);
#pragma unroll
      for (int nj = 0; nj < 4; nj++) {
        const unsigned short* krow = Kb + (nj * 16 + lr) * 64;
        bf16x8 kb0 = *(const bf16x8*)(krow + ((lg * 8) ^ swr));
        bf16x8 kb1 = *(const bf16x8*)(krow + ((32 + lg * 8) ^ swr));
        f32x4 zA = (f32x4){0.f, 0.f, 0.f, 0.f};
        f32x4 zB = (f32x4){0.f, 0.f, 0.f, 0.f};
        zA = __builtin_amdgcn_mfma_f32_16x16x32_bf16(kb0, aqA0, zA, 0, 0, 0);
        zA = __builtin_amdgcn_mfma_f32_16x16x32_bf16(kb1, aqA1, zA, 0, 0, 0);
        zB = __builtin_amdgcn_mfma_f32_16x16x32_bf16(kb0, aqB0, zB, 0, 0, 0);
        zB = __builtin_amdgcn_mfma_f32_16x16x32_bf16(kb1, aqB1, zB, 0, 0, 0);
        sA[nj] = zA;
        sB[nj] = zB;
      }
      __builtin_amdgcn_s_setprio(0);

      // causal mask only on the wave's diagonal tile
      if (i == diagw) {
        const int qrA = q0 + lr, qrB = q0 + 16 + lr;
#pragma unroll
        for (int nj = 0; nj < 4; nj++) {
#pragma unroll
          for (int r = 0; r < 4; r++) {
            const int key = kv0 + nj * 16 + lg * 4 + r;
            if (key > qrA) sA[nj][r] = -__builtin_inff();
            if (key > qrB) sB[nj][r] = -__builtin_inff();
          }
        }
      }

      // lane-local per-row max (lane owns 16 of row's 64 keys)
      float pmA = sA[0][0], pmB = sB[0][0];
#pragma unroll
      for (int nj = 0; nj < 4; nj++)
#pragma unroll
        for (int r = 0; r < 4; r++) {
          pmA = fmaxf(pmA, sA[nj][r]);
          pmB = fmaxf(pmB, sB[nj][r]);
        }

      // defer-max (T13, THR=8): row max <= m+8 iff all 4 owner lanes agree
      const bool okl = (pmA <= mA + 8.f) & (pmB <= mB + 8.f);
      if (!__all(okl)) {                 // rare: first tile + rare growth
        // full row max across the 4 owner lanes (xor 16, 32)
        pmA = fmaxf(pmA, __shfl_xor(pmA, 16));
        pmA = fmaxf(pmA, __shfl_xor(pmA, 32));
        pmB = fmaxf(pmB, __shfl_xor(pmB, 16));
        pmB = fmaxf(pmB, __shfl_xor(pmB, 32));
        const float mnA = fmaxf(mA, pmA), mnB = fmaxf(mB, pmB);
        const float scA = exp2f(mA - mnA), scB = exp2f(mB - mnB);
        mA = mnA; mB = mnB;
        lA *= scA; lB *= scB;
#pragma unroll
        for (int r = 0; r < 4; r++) {
          const float cA = __shfl(scA, lg * 4 + r);  // sc of row lg*4+r
          const float cB = __shfl(scB, lg * 4 + r);
#pragma unroll
          for (int dj = 0; dj < 4; dj++) {
            oA[dj][r] *= cA;
            oB[dj][r] *= cB;
          }
        }
      }

      // P = exp2(s - m) -> bf16x4 packed swizzled writes
#pragma unroll
      for (int nj = 0; nj < 4; nj++) {
        const float a0 = exp2f(sA[nj][0] - mA), a1 = exp2f(sA[nj][1] - mA);
        const float a2 = exp2f(sA[nj][2] - mA), a3 = exp2f(sA[nj][3] - mA);
        lA += (a0 + a1) + (a2 + a3);
        bf16x4 pkA = {(__bf16)a0, (__bf16)a1, (__bf16)a2, (__bf16)a3};
        *(bf16x4*)(Pw + lr * 72 + ((nj * 16 + lg * 4) ^ pswz)) = pkA;
        const float b0 = exp2f(sB[nj][0] - mB), b1 = exp2f(sB[nj][1] - mB);
        const float b2 = exp2f(sB[nj][2] - mB), b3 = exp2f(sB[nj][3] - mB);
        lB += (b0 + b1) + (b2 + b3);
        bf16x4 pkB = {(__bf16)b0, (__bf16)b1, (__bf16)b2, (__bf16)b3};
        *(bf16x4*)(Pw + (16 + lr) * 72 + ((nj * 16 + lg * 4) ^ pswz)) = pkB;
      }

      // PV A-fragments (same swizzle mask on reads; in-wave DS ordering)
      bf16x8 paA0 = *(const bf16x8*)(Pw + lr * 72 + ((lg * 8) ^ pswz));
      bf16x8 paA1 = *(const bf16x8*)(Pw + lr * 72 + ((32 + lg * 8) ^ pswz));
      bf16x8 paB0 = *(const bf16x8*)(Pw + (16 + lr) * 72 + ((lg * 8) ^ pswz));
      bf16x8 paB1 = *(const bf16x8*)(Pw + (16 + lr) * 72 + ((32 + lg * 8) ^ pswz));

      // PV: O += P[32,64] * V^T (vb shared across halves)
      __builtin_amdgcn_s_setprio(1);
#pragma unroll
      for (int dj = 0; dj < 4; dj++) {
        const unsigned short* vrow = Vb + (dj * 16 + lr) * 64;
        bf16x8 vb0 = *(const bf16x8*)(vrow + ((lg * 8) ^ swr));
        bf16x8 vb1 = *(const bf16x8*)(vrow + ((32 + lg * 8) ^ swr));
        oA[dj] = __builtin_amdgcn_mfma_f32_16x16x32_bf16(paA0, vb0, oA[dj], 0, 0, 0);
        oA[dj] = __builtin_amdgcn_mfma_f32_16x16x32_bf16(paA1, vb1, oA[dj], 0, 0, 0);
        oB[dj] = __builtin_amdgcn_mfma_f32_16x16x32_bf16(paB0, vb0, oB[dj], 0, 0, 0);
        oB[dj] = __builtin_amdgcn_mfma_f32_16x16x32_bf16(paB1, vb1, oB[dj], 0, 0, 0);
      }
      __builtin_amdgcn_s_setprio(0);
    }
  }

  // finalize l: full row sums (partials live on the 4 owner lanes)
  lA += __shfl_xor(lA, 16); lA += __shfl_xor(lA, 32);
  lB += __shfl_xor(lB, 16); lB += __shfl_xor(lB, 32);

  if (kind == 2) {
    // unsplit: normalize, write bf16 [B,T,C] (heads re-merged)
    __bf16* yb = (__bf16*)yatt;
#pragma unroll
    for (int r = 0; r < 4; r++) {
      const float invA = 1.0f / __shfl(lA, lg * 4 + r);
      const float invB = 1.0f / __shfl(lB, lg * 4 + r);
      const int tA = q0 + lg * 4 + r;
      const int tB = tA + 16;
      const size_t baseA = ((size_t)(bb * 2048 + tA)) * 1024 + hh * 64;
      const size_t baseB = ((size_t)(bb * 2048 + tB)) * 1024 + hh * 64;
#pragma unroll
      for (int dj = 0; dj < 4; dj++) {
        yb[baseA + dj * 16 + lr] = (__bf16)(oA[dj][r] * invA);
        yb[baseB + dj * 16 + lr] = (__bf16)(oB[dj][r] * invB);
      }
    }
  } else {
    // split half: write unnormalized partial O (bf16) + m,l (f32)
    __bf16* Ob = (__bf16*)Opart;
#pragma unroll
    for (int r = 0; r < 4; r++) {
      const int slotA = bh * 1536 + (q0 + lg * 4 + r) - 512;
      const int slotB = slotA + 16;
      const size_t baseA = ((size_t)(kind * 49152 + slotA)) * 64;
      const size_t baseB = ((size_t)(kind * 49152 + slotB)) * 64;
#pragma unroll
      for (int dj = 0; dj < 4; dj++) {
        Ob[baseA + dj * 16 + lr] = (__bf16)oA[dj][r];
        Ob[baseB + dj * 16 + lr] = (__bf16)oB[dj][r];
      }
    }
    if (lg == 0) {                       // one writer per row
      const int slA = bh * 1536 + (q0 + lr) - 512;
      Mp[kind * 49152 + slA] = mA;
      Lp[kind * 49152 + slA] = lA;
      Mp[kind * 49152 + slA + 16] = mB;
      Lp[kind * 49152 + slA + 16] = lB;
    }
  }
}

// combine L/R partials: y = (O1*2^(m1-m) + O2*2^(m2-m)) / (l1*2^(m1-m)+l2*2^(m2-m))
__global__ void __launch_bounds__(256) attn_merge(
    const unsigned short* __restrict__ Op, const float* __restrict__ Mp,
    const float* __restrict__ Lp, unsigned short* __restrict__ yatt) {
  const int gid = blockIdx.x * 256 + threadIdx.x;  // 48*256 = 12288 per bh
  const int sl = gid >> 3;                         // 0..1535
  const int d0 = (gid & 7) * 8;
  const int bh = blockIdx.y;
  const int slot = bh * 1536 + sl;
  const float m1 = Mp[slot], m2 = Mp[49152 + slot];
  const float l1 = Lp[slot], l2 = Lp[49152 + slot];
  const float mx = fmaxf(m1, m2);
  const float w1 = exp2f(m1 - mx), w2 = exp2f(m2 - mx);
  const float inv = 1.0f / (l1 * w1 + l2 * w2);
  u16x8 a = *(const u16x8*)(Op + (size_t)slot * 64 + d0);
  u16x8 b = *(const u16x8*)(Op + (size_t)(49152 + slot) * 64 + d0);
  const int qr = 512 + sl;
  unsigned short* dst = yatt +
      ((size_t)((bh >> 4) * 2048 + qr)) * 1024 + (bh & 15) * 64 + d0;
  u16x8 o;
#pragma unroll
  for (int j = 0; j < 8; j++)
    o[j] = f2b((b2f(a[j]) * w1 + b2f(b[j]) * w2) * inv);
  *(u16x8*)dst = o;
}

// ---------------- launcher ----------------

extern "C" void kernel_launch(void* const* d_in, const int* in_sizes, int n_in,
                              void* d_out, int out_size, void* d_ws,
                              size_t ws_size, hipStream_t stream) {
  (void)in_sizes; (void)n_in; (void)out_size; (void)ws_size;
  const float* x      = (const float*)d_in[0];  // [2,2048,1024]
  const float* w_qkv  = (const float*)d_in[1];  // [1024,3072]
  const float* b_qkv  = (const float*)d_in[2];  // [3072]
  const float* w_proj = (const float*)d_in[3];  // [1024,1024]
  const float* b_proj = (const float*)d_in[4];  // [1024]
  float* out = (float*)d_out;                   // [2,2048,1024] f32

  unsigned short* ws     = (unsigned short*)d_ws;
  unsigned short* xb     = ws;                                  // 4096*1024
  unsigned short* wqkvT  = xb     + (size_t)4096 * 1024;        // 3072*1024
  unsigned short* wprojT = wqkvT  + (size_t)3072 * 1024;        // 1024*1024
  unsigned short* Qh     = wprojT + (size_t)1024 * 1024;        // 2*16*2048*64
  unsigned short* Kh     = Qh     + (size_t)2 * 16 * 2048 * 64;
  unsigned short* Vh     = Kh     + (size_t)2 * 16 * 2048 * 64; // [B,H,D,T]
  unsigned short* yatt   = Vh     + (size_t)2 * 16 * 2048 * 64; // 4096*1024

  // attn partials alias xb/wqkvT (dead after QKV GEMM); wprojT untouched.
  unsigned short* Opart = ws;                      // [2][49152][64] bf16
  float* Mp = (float*)(ws + (size_t)6291456);      // [2][49152] f32
  float* Lp = Mp + 2 * 49152;                      // [2][49152] f32

  cvt_f32_to_bf16<<<4096, 256, 0, stream>>>(x, xb, 1048576);
  transpose_f32_to_bf16<<<dim3(96, 32), dim3(32, 8), 0, stream>>>(w_qkv, wqkvT, 1024, 3072);
  transpose_f32_to_bf16<<<dim3(32, 32), dim3(32, 8), 0, stream>>>(w_proj, wprojT, 1024, 1024);

  gemm_bt<0><<<dim3(32, 24), 256, 0, stream>>>(xb, wqkvT, b_qkv, Qh, Kh, Vh,
                                               nullptr, 4096, 3072, 1024);
  attn_kernel<<<896, 256, 0, stream>>>(Qh, Kh, Vh, yatt, Opart, Mp, Lp);
  attn_merge<<<dim3(48, 32), 256, 0, stream>>>(Opart, Mp, Lp, yatt);
  gemm_bt<1><<<dim3(32, 8), 256, 0, stream>>>(yatt, wprojT, b_proj, nullptr,
                                              nullptr, nullptr, out, 4096, 1024, 1024);
}